// Round 1
// baseline (238.972 us; speedup 1.0000x reference)
//
#include <hip/hip_runtime.h>
#include <hip/hip_bf16.h>
#include <math.h>

#define NLVL 4
#define NSLOT 32768
#define DZ 128
#define DV 512
#define DK 128
#define SBLK 64  // score blocks per level

__device__ inline void atomicMaxFloat(float* addr, float val) {
    unsigned int* ua = (unsigned int*)addr;
    unsigned int old = *ua;
    while (__uint_as_float(old) < val) {
        unsigned int assumed = old;
        old = atomicCAS(ua, assumed, __float_as_uint(val));
        if (old == assumed) break;
    }
}

// K1: per-level features. grid = NLVL blocks, 256 threads.
__global__ __launch_bounds__(256) void k_features(
    const float* __restrict__ s_t, const float* __restrict__ e_t,
    const float* __restrict__ ctx,
    const float* __restrict__ W1_0, const float* __restrict__ b1_0,
    const float* __restrict__ W1_r, const float* __restrict__ b1_r,
    const float* __restrict__ spec_wr,
    const float* __restrict__ ln_g, const float* __restrict__ ln_b,
    const float* __restrict__ Wg, const float* __restrict__ bg,
    const float* __restrict__ Wv, const float* __restrict__ bv,
    const float* __restrict__ Wk, const float* __restrict__ bk,
    const float* __restrict__ decay,
    float* __restrict__ kvec, float* __restrict__ vvec,
    float* __restrict__ wgt_out, float* __restrict__ maxb,
    float* __restrict__ keepb)
{
    const int ell = blockIdx.x;
    const int tid = threadIdx.x;
    __shared__ float sx[2560];
    __shared__ float sz[DZ];
    __shared__ float ph[256];

    // build x = [s_t, (ctx[ell-1]), e_t]
    if (ell == 0) {
        for (int i = tid; i < 1024; i += 256) { sx[i] = s_t[i]; sx[1024 + i] = e_t[i]; }
    } else {
        for (int i = tid; i < 1024; i += 256) { sx[i] = s_t[i]; sx[1536 + i] = e_t[i]; }
        for (int i = tid; i < 512; i += 256) sx[1024 + i] = ctx[(ell - 1) * 512 + i];
    }
    __syncthreads();

    const int d = (ell == 0) ? 2048 : 2560;
    const float* W1 = (ell == 0) ? W1_0 : (W1_r + (size_t)(ell - 1) * 128 * 2560);
    const float* b1 = (ell == 0) ? b1_0 : (b1_r + (ell - 1) * 128);

    // h row dot: 2 threads per row (halves)
    const int row = tid & 127;
    const int half = tid >> 7;
    const int hlen = d >> 1;
    const float* wrow = W1 + (size_t)row * d + half * hlen;
    const float* xrow = sx + half * hlen;
    float acc = 0.f;
    for (int i = 0; i < hlen; i += 4) {
        float4 w = *(const float4*)(wrow + i);
        acc += w.x * xrow[i] + w.y * xrow[i + 1] + w.z * xrow[i + 2] + w.w * xrow[i + 3];
    }
    ph[tid] = acc;
    __syncthreads();

    // y = h * spec_wr   (rfft/irfft with n=1 => real part of h*(wr+i*wi) = h*wr)
    if (tid < 128) {
        float h = ph[tid] + ph[tid + 128] + b1[tid];
        sz[tid] = h * spec_wr[ell * 128 + tid];
    }
    __syncthreads();

    // layernorm (redundant scalar reduce over 128 — trivial)
    float mu = 0.f;
    for (int i = 0; i < 128; ++i) mu += sz[i];
    mu *= (1.f / 128.f);
    float var = 0.f;
    for (int i = 0; i < 128; ++i) { float dd = sz[i] - mu; var += dd * dd; }
    var *= (1.f / 128.f);
    float rstd = rsqrtf(var + 1e-5f);
    __syncthreads();
    if (tid < 128) {
        sz[tid] = (sz[tid] - mu) * rstd * ln_g[ell * 128 + tid] + ln_b[ell * 128 + tid];
    }
    __syncthreads();

    // gate
    float gdot = 0.f;
    for (int i = 0; i < 128; ++i) gdot += Wg[ell * 128 + i] * sz[i];
    float g = 1.f / (1.f + expf(-(gdot + bg[ell])));
    float w = (g >= 0.1f) ? g : 0.f;

    // v = tanh(Wv z + bv)
    for (int r = tid; r < 512; r += 256) {
        const float* wv = Wv + (size_t)ell * 512 * 128 + (size_t)r * 128;
        float a = 0.f;
        #pragma unroll
        for (int i = 0; i < 128; i += 4) {
            float4 ww = *(const float4*)(wv + i);
            a += ww.x * sz[i] + ww.y * sz[i + 1] + ww.z * sz[i + 2] + ww.w * sz[i + 3];
        }
        vvec[ell * 512 + r] = tanhf(a + bv[ell * 512 + r]);
    }
    // k = Wk z + bk
    if (tid < 128) {
        const float* wk = Wk + (size_t)ell * 128 * 128 + (size_t)tid * 128;
        float a = 0.f;
        #pragma unroll
        for (int i = 0; i < 128; i += 4) {
            float4 ww = *(const float4*)(wk + i);
            a += ww.x * sz[i] + ww.y * sz[i + 1] + ww.z * sz[i + 2] + ww.w * sz[i + 3];
        }
        kvec[ell * 128 + tid] = a + bk[ell * 128 + tid];
    }
    if (tid == 0) {
        wgt_out[ell] = w;
        maxb[ell] = -INFINITY;
        keepb[ell] = 1.f - decay[ell];
    }
}

// K2: scores + block max. grid = (SBLK, NLVL), 256 threads.
__global__ __launch_bounds__(256) void k_scores(
    const float* __restrict__ K_mem, const float* __restrict__ kvec,
    float* __restrict__ scores, float* __restrict__ maxb)
{
    const int ell = blockIdx.y;
    const int tid = threadIdx.x;
    __shared__ float sk[DK];
    __shared__ float sm[256];
    if (tid < DK) sk[tid] = kvec[ell * DK + tid];
    __syncthreads();

    const int slots = NSLOT / SBLK;         // 512
    const int n0 = blockIdx.x * slots;
    const float scale = 0.088388347648318447f; // 1/sqrt(128)
    float lmax = -INFINITY;
    for (int s = tid; s < slots; s += 256) {
        int n = n0 + s;
        const float* kr = K_mem + ((size_t)ell * NSLOT + n) * DK;
        float a = 0.f;
        #pragma unroll
        for (int i = 0; i < DK; i += 4) {
            float4 ww = *(const float4*)(kr + i);
            a += ww.x * sk[i] + ww.y * sk[i + 1] + ww.z * sk[i + 2] + ww.w * sk[i + 3];
        }
        a *= scale;
        scores[ell * NSLOT + n] = a;
        lmax = fmaxf(lmax, a);
    }
    sm[tid] = lmax;
    __syncthreads();
    for (int off = 128; off > 0; off >>= 1) {
        if (tid < off) sm[tid] = fmaxf(sm[tid], sm[tid + off]);
        __syncthreads();
    }
    if (tid == 0) atomicMaxFloat(&maxb[ell], sm[0]);
}

// K3: softmax finish: scores[n] <- wgt * exp(s - max)/denom. grid = NLVL, 1024 thr.
__global__ __launch_bounds__(1024) void k_softmax(
    float* __restrict__ scores, const float* __restrict__ maxb,
    const float* __restrict__ wgt)
{
    const int ell = blockIdx.x;
    const int tid = threadIdx.x;
    __shared__ float sm[1024];
    __shared__ float sscale;
    const float m = maxb[ell];
    float* sc = scores + (size_t)ell * NSLOT;
    float lsum = 0.f;
    for (int n = tid; n < NSLOT; n += 1024) {
        float e = expf(sc[n] - m);
        sc[n] = e;
        lsum += e;
    }
    sm[tid] = lsum;
    __syncthreads();
    for (int off = 512; off > 0; off >>= 1) {
        if (tid < off) sm[tid] += sm[tid + off];
        __syncthreads();
    }
    if (tid == 0) sscale = wgt[ell] / sm[0];
    __syncthreads();
    const float scl = sscale;
    for (int n = tid; n < NSLOT; n += 1024) sc[n] *= scl;
}

// K4: streaming write. grid-stride over float4s of out [L,N,640].
__global__ __launch_bounds__(256) void k_write(
    const float* __restrict__ M, const float* __restrict__ K_mem,
    const float* __restrict__ coef,
    const float* __restrict__ vvec, const float* __restrict__ kvec,
    const float* __restrict__ keepb, float4* __restrict__ out)
{
    __shared__ float4 sv4[NLVL * 128]; // v: 4 levels x 512 floats
    __shared__ float4 sk4[NLVL * 32];  // k: 4 levels x 128 floats
    __shared__ float skeep[NLVL];
    const int tid = threadIdx.x;
    const float4* vg = (const float4*)vvec;
    const float4* kg = (const float4*)kvec;
    for (int i = tid; i < NLVL * 128; i += 256) sv4[i] = vg[i];
    for (int i = tid; i < NLVL * 32; i += 256) sk4[i] = kg[i];
    if (tid < NLVL) skeep[tid] = keepb[tid];
    __syncthreads();

    const int total = NLVL * NSLOT * 160; // 20,971,520 float4
    const int stride = gridDim.x * blockDim.x;
    for (int idx = blockIdx.x * blockDim.x + tid; idx < total; idx += stride) {
        int row = idx / 160;
        int j4 = idx - row * 160;
        int ell = row >> 15;
        float c = coef[row];
        float keep = skeep[ell];
        float4 o;
        if (j4 < 128) {
            float4 m = ((const float4*)M)[(size_t)row * 128 + j4];
            float4 vv = sv4[(ell << 7) + j4];
            o.x = keep * m.x + c * vv.x;
            o.y = keep * m.y + c * vv.y;
            o.z = keep * m.z + c * vv.z;
            o.w = keep * m.w + c * vv.w;
        } else {
            int jk = j4 - 128;
            float4 kk = ((const float4*)K_mem)[(size_t)row * 32 + jk];
            float4 kv = sk4[(ell << 5) + jk];
            o.x = keep * kk.x + c * kv.x;
            o.y = keep * kk.y + c * kv.y;
            o.z = keep * kk.z + c * kv.z;
            o.w = keep * kk.w + c * kv.w;
        }
        out[idx] = o;
    }
}

extern "C" void kernel_launch(void* const* d_in, const int* in_sizes, int n_in,
                              void* d_out, int out_size, void* d_ws, size_t ws_size,
                              hipStream_t stream) {
    const float* s_t    = (const float*)d_in[0];
    const float* e_t    = (const float*)d_in[1];
    const float* ctx    = (const float*)d_in[2];
    const float* M      = (const float*)d_in[3];
    const float* K_mem  = (const float*)d_in[4];
    const float* decay  = (const float*)d_in[5];
    const float* W1_0   = (const float*)d_in[6];
    const float* b1_0   = (const float*)d_in[7];
    const float* W1_r   = (const float*)d_in[8];
    const float* b1_r   = (const float*)d_in[9];
    const float* spec_wr= (const float*)d_in[10];
    // d_in[11] = spec_wi: unused — irfft(n=1) keeps only the real part
    const float* ln_g   = (const float*)d_in[12];
    const float* ln_b   = (const float*)d_in[13];
    const float* Wg     = (const float*)d_in[14];
    const float* bg     = (const float*)d_in[15];
    const float* Wv     = (const float*)d_in[16];
    const float* bv     = (const float*)d_in[17];
    const float* Wk     = (const float*)d_in[18];
    const float* bk     = (const float*)d_in[19];

    float* ws = (float*)d_ws;
    float* coef  = ws;                         // L*N = 131072
    float* kvec  = ws + 131072;                // L*128 = 512
    float* vvec  = ws + 131584;                // L*512 = 2048
    float* wgt   = ws + 133632;                // L
    float* maxb  = ws + 133636;                // L
    float* keepb = ws + 133640;                // L

    k_features<<<NLVL, 256, 0, stream>>>(
        s_t, e_t, ctx, W1_0, b1_0, W1_r, b1_r, spec_wr, ln_g, ln_b,
        Wg, bg, Wv, bv, Wk, bk, decay, kvec, vvec, wgt, maxb, keepb);

    dim3 g2(SBLK, NLVL);
    k_scores<<<g2, 256, 0, stream>>>(K_mem, kvec, coef, maxb);

    k_softmax<<<NLVL, 1024, 0, stream>>>(coef, maxb, wgt);

    k_write<<<2048, 256, 0, stream>>>(M, K_mem, coef, vvec, kvec, keepb,
                                      (float4*)d_out);
}

// Round 4
// 150.943 us; speedup vs baseline: 1.5832x; 1.5832x over previous
//
#include <hip/hip_runtime.h>
#include <hip/hip_bf16.h>
#include <math.h>

#define NLVL 4
#define NSLOT 32768
#define SB 128          // score blocks per level

typedef float f4 __attribute__((ext_vector_type(4)));

// ---------------------------------------------------------------------------
// K_h: h-row dots. grid = (128 rows, 4 levels), 256 threads.
// h = W1 @ x + b1 ; y = h * spec_wr  (irfft(n=1) keeps only the real part)
__global__ __launch_bounds__(256) void k_h(
    const float* __restrict__ s_t, const float* __restrict__ e_t,
    const float* __restrict__ ctx,
    const float* __restrict__ W1_0, const float* __restrict__ b1_0,
    const float* __restrict__ W1_r, const float* __restrict__ b1_r,
    const float* __restrict__ spec_wr, float* __restrict__ ybuf)
{
    const int row = blockIdx.x;
    const int ell = blockIdx.y;
    const int tid = threadIdx.x;
    const int d = (ell == 0) ? 2048 : 2560;
    const float* W1 = (ell == 0) ? W1_0 : (W1_r + (size_t)(ell - 1) * 128 * 2560);
    const float* b1 = (ell == 0) ? b1_0 : (b1_r + (ell - 1) * 128);
    const f4* wrow = (const f4*)(W1 + (size_t)row * d);

    float acc = 0.f;
    if (ell == 0) {
        for (int i4 = tid; i4 < 512; i4 += 256) {
            f4 w = wrow[i4];
            f4 x = (i4 < 256) ? ((const f4*)s_t)[i4]
                              : ((const f4*)e_t)[i4 - 256];
            acc += w.x * x.x + w.y * x.y + w.z * x.z + w.w * x.w;
        }
    } else {
        const f4* c4 = (const f4*)(ctx + (size_t)(ell - 1) * 512);
        for (int i4 = tid; i4 < 640; i4 += 256) {
            f4 w = wrow[i4];
            f4 x;
            if (i4 < 256)      x = ((const f4*)s_t)[i4];
            else if (i4 < 384) x = c4[i4 - 256];
            else               x = ((const f4*)e_t)[i4 - 384];
            acc += w.x * x.x + w.y * x.y + w.z * x.z + w.w * x.w;
        }
    }
    __shared__ float red[256];
    red[tid] = acc;
    __syncthreads();
    for (int off = 128; off > 0; off >>= 1) {
        if (tid < off) red[tid] += red[tid + off];
        __syncthreads();
    }
    if (tid == 0)
        ybuf[ell * 128 + row] = (red[0] + b1[row]) * spec_wr[ell * 128 + row];
}

// ---------------------------------------------------------------------------
// K_z: layernorm + gate. grid = 4 blocks, 128 threads.
__global__ __launch_bounds__(128) void k_z(
    const float* __restrict__ ybuf,
    const float* __restrict__ ln_g, const float* __restrict__ ln_b,
    const float* __restrict__ Wg, const float* __restrict__ bg,
    const float* __restrict__ decay,
    float* __restrict__ zbuf, float* __restrict__ wgt, float* __restrict__ keepb)
{
    const int ell = blockIdx.x;
    const int t = threadIdx.x;
    __shared__ float red[128];
    float y = ybuf[ell * 128 + t];
    red[t] = y;
    __syncthreads();
    for (int off = 64; off > 0; off >>= 1) {
        if (t < off) red[t] += red[t + off];
        __syncthreads();
    }
    float mu = red[0] * (1.f / 128.f);
    __syncthreads();
    float dd = y - mu;
    red[t] = dd * dd;
    __syncthreads();
    for (int off = 64; off > 0; off >>= 1) {
        if (t < off) red[t] += red[t + off];
        __syncthreads();
    }
    float rstd = rsqrtf(red[0] * (1.f / 128.f) + 1e-5f);
    float z = dd * rstd * ln_g[ell * 128 + t] + ln_b[ell * 128 + t];
    zbuf[ell * 128 + t] = z;
    __syncthreads();
    red[t] = Wg[ell * 128 + t] * z;
    __syncthreads();
    for (int off = 64; off > 0; off >>= 1) {
        if (t < off) red[t] += red[t + off];
        __syncthreads();
    }
    if (t == 0) {
        float g = 1.f / (1.f + expf(-(red[0] + bg[ell])));
        wgt[ell] = (g >= 0.1f) ? g : 0.f;
        keepb[ell] = 1.f - decay[ell];
    }
}

// ---------------------------------------------------------------------------
// K_vk: v = tanh(Wv z + bv), k = Wk z + bk. grid = (10, 4), 256 threads.
// 64 rows/block, 4 lanes per row of 128.
__global__ __launch_bounds__(256) void k_vk(
    const float* __restrict__ zbuf,
    const float* __restrict__ Wv, const float* __restrict__ bv,
    const float* __restrict__ Wk, const float* __restrict__ bk,
    float* __restrict__ vvec, float* __restrict__ kvec)
{
    const int ell = blockIdx.y;
    const int tid = threadIdx.x;
    __shared__ float sz[128];
    if (tid < 128) sz[tid] = zbuf[ell * 128 + tid];
    __syncthreads();

    const int r = blockIdx.x * 64 + (tid >> 2);  // 0..639
    const int lane = tid & 3;
    const float* wrow;
    float bias;
    float* outp;
    bool is_v = (r < 512);
    if (is_v) {
        wrow = Wv + ((size_t)ell * 512 + r) * 128;
        bias = bv[ell * 512 + r];
        outp = vvec + ell * 512 + r;
    } else {
        int rk = r - 512;
        wrow = Wk + ((size_t)ell * 128 + rk) * 128;
        bias = bk[ell * 128 + rk];
        outp = kvec + ell * 128 + rk;
    }
    float a = 0.f;
    const f4* w4 = (const f4*)wrow + lane * 8;
    const float* z0 = sz + lane * 32;
    #pragma unroll
    for (int j = 0; j < 8; ++j) {
        f4 w = w4[j];
        a += w.x * z0[j * 4] + w.y * z0[j * 4 + 1] + w.z * z0[j * 4 + 2] + w.w * z0[j * 4 + 3];
    }
    a += __shfl_xor(a, 1);
    a += __shfl_xor(a, 2);
    if (lane == 0) {
        float val = a + bias;
        if (is_v) val = tanhf(val);
        *outp = val;
    }
}

// ---------------------------------------------------------------------------
// K_scores: e = exp(score), per-block partial sums. grid = (SB, 4), 256 thr.
// 16 lanes per row, 2 consecutive float4 per lane (coalesced 2KB per wave).
__global__ __launch_bounds__(256) void k_scores(
    const float* __restrict__ K_mem, const float* __restrict__ kvec,
    float* __restrict__ expsc, float* __restrict__ partial)
{
    const int ell = blockIdx.y;
    const int tid = threadIdx.x;
    __shared__ float sk[128];
    __shared__ float red[256];
    if (tid < 128) sk[tid] = kvec[ell * 128 + tid];
    __syncthreads();

    const int n0 = blockIdx.x * (NSLOT / SB);   // 256 rows per block
    const int gid = tid >> 4, lane = tid & 15;
    const float* z0 = sk + lane * 8;
    const float scale = 0.08838834764831845f;   // 1/sqrt(128)
    float acc = 0.f;
    for (int it = 0; it < 16; ++it) {
        int n = n0 + it * 16 + gid;
        const f4* kr = (const f4*)(K_mem + ((size_t)ell * NSLOT + n) * 128) + lane * 2;
        f4 wa = kr[0], wb = kr[1];
        float a = wa.x * z0[0] + wa.y * z0[1] + wa.z * z0[2] + wa.w * z0[3]
                + wb.x * z0[4] + wb.y * z0[5] + wb.z * z0[6] + wb.w * z0[7];
        #pragma unroll
        for (int m = 1; m < 16; m <<= 1) a += __shfl_xor(a, m);
        if (lane == 0) {
            float e = expf(a * scale);
            expsc[(size_t)ell * NSLOT + n] = e;
            acc += e;
        }
    }
    red[tid] = acc;
    __syncthreads();
    for (int off = 128; off > 0; off >>= 1) {
        if (tid < off) red[tid] += red[tid + off];
        __syncthreads();
    }
    if (tid == 0) partial[ell * SB + blockIdx.x] = red[0];
}

// ---------------------------------------------------------------------------
// K_write: out = keep*[M|K] + (wgt*alpha)*[v|k]. grid-stride over float4s.
__global__ __launch_bounds__(256) void k_write(
    const float* __restrict__ M, const float* __restrict__ K_mem,
    const float* __restrict__ expsc, const float* __restrict__ partial,
    const float* __restrict__ wgt, const float* __restrict__ keepb,
    const float* __restrict__ vvec, const float* __restrict__ kvec,
    f4* __restrict__ out)
{
    __shared__ f4 sv4[512];   // v: 4 x 512 floats
    __shared__ f4 sk4[128];   // k: 4 x 128 floats
    __shared__ float sp[512];
    __shared__ float sscl[4], skeep[4];
    const int tid = threadIdx.x;
    for (int i = tid; i < 512; i += 256) {
        sv4[i] = ((const f4*)vvec)[i];
        sp[i] = partial[i];
    }
    for (int i = tid; i < 128; i += 256) sk4[i] = ((const f4*)kvec)[i];
    __syncthreads();
    if (tid < 4) {
        float s = 0.f;
        for (int j = 0; j < SB; ++j) s += sp[tid * SB + j];   // deterministic order
        sscl[tid] = wgt[tid] / s;
        skeep[tid] = keepb[tid];
    }
    __syncthreads();

    const int total = NLVL * NSLOT * 160;
    const int stride = gridDim.x * blockDim.x;
    for (int idx = blockIdx.x * blockDim.x + tid; idx < total; idx += stride) {
        int row = idx / 160;
        int j4 = idx - row * 160;
        int ell = row >> 15;
        float c = expsc[row] * sscl[ell];
        float keep = skeep[ell];
        f4 o;
        if (j4 < 128) {
            f4 m = __builtin_nontemporal_load((const f4*)M + (size_t)row * 128 + j4);
            f4 vv = sv4[(ell << 7) + j4];
            o.x = keep * m.x + c * vv.x;
            o.y = keep * m.y + c * vv.y;
            o.z = keep * m.z + c * vv.z;
            o.w = keep * m.w + c * vv.w;
        } else {
            int jk = j4 - 128;
            f4 kk = __builtin_nontemporal_load((const f4*)K_mem + (size_t)row * 32 + jk);
            f4 kv = sk4[(ell << 5) + jk];
            o.x = keep * kk.x + c * kv.x;
            o.y = keep * kk.y + c * kv.y;
            o.z = keep * kk.z + c * kv.z;
            o.w = keep * kk.w + c * kv.w;
        }
        __builtin_nontemporal_store(o, out + idx);
    }
}

extern "C" void kernel_launch(void* const* d_in, const int* in_sizes, int n_in,
                              void* d_out, int out_size, void* d_ws, size_t ws_size,
                              hipStream_t stream) {
    const float* s_t    = (const float*)d_in[0];
    const float* e_t    = (const float*)d_in[1];
    const float* ctx    = (const float*)d_in[2];
    const float* M      = (const float*)d_in[3];
    const float* K_mem  = (const float*)d_in[4];
    const float* decay  = (const float*)d_in[5];
    const float* W1_0   = (const float*)d_in[6];
    const float* b1_0   = (const float*)d_in[7];
    const float* W1_r   = (const float*)d_in[8];
    const float* b1_r   = (const float*)d_in[9];
    const float* spec_wr= (const float*)d_in[10];
    // d_in[11] = spec_wi: unused — irfft(n=1) keeps only the real part
    const float* ln_g   = (const float*)d_in[12];
    const float* ln_b   = (const float*)d_in[13];
    const float* Wg     = (const float*)d_in[14];
    const float* bg     = (const float*)d_in[15];
    const float* Wv     = (const float*)d_in[16];
    const float* bv     = (const float*)d_in[17];
    const float* Wk     = (const float*)d_in[18];
    const float* bk     = (const float*)d_in[19];

    float* ws = (float*)d_ws;
    float* expsc   = ws;                 // L*N            = 131072
    float* partial = ws + 131072;        // L*SB           = 512
    float* ybuf    = ws + 131584;        // L*128          = 512
    float* zbuf    = ws + 132096;        // L*128          = 512
    float* kvec    = ws + 132608;        // L*128          = 512
    float* vvec    = ws + 133120;        // L*512          = 2048
    float* wgt     = ws + 135168;        // L
    float* keepb   = ws + 135172;        // L

    dim3 gh(128, NLVL);
    k_h<<<gh, 256, 0, stream>>>(s_t, e_t, ctx, W1_0, b1_0, W1_r, b1_r,
                                spec_wr, ybuf);

    k_z<<<NLVL, 128, 0, stream>>>(ybuf, ln_g, ln_b, Wg, bg, decay,
                                  zbuf, wgt, keepb);

    dim3 gvk(10, NLVL);
    k_vk<<<gvk, 256, 0, stream>>>(zbuf, Wv, bv, Wk, bk, vvec, kvec);

    dim3 gs(SB, NLVL);
    k_scores<<<gs, 256, 0, stream>>>(K_mem, kvec, expsc, partial);

    k_write<<<2048, 256, 0, stream>>>(M, K_mem, expsc, partial, wgt, keepb,
                                      vvec, kvec, (f4*)d_out);
}